// Round 16
// baseline (157.697 us; speedup 1.0000x reference)
//
#include <hip/hip_runtime.h>
#include <stdint.h>

#define M_DIM 1024
#define K_DIM 4096
#define N_DIM 11008
#define NPACK 1376
#define NGROUPS 32
#define K8 (K_DIM / 8)      // 512

#define BM 128
#define BN 128
#define BK 64
#define ATILE (BM * BK)     // 8192 shorts = 16 KiB

typedef __attribute__((ext_vector_type(16))) float f32x16;
typedef __attribute__((ext_vector_type(4))) float f32x4;
typedef __attribute__((ext_vector_type(8))) _Float16 f16x8;
typedef __attribute__((ext_vector_type(2))) _Float16 h2;

static __device__ __forceinline__ unsigned swz(unsigned r) {
  return (r ^ (r >> 3)) & 7u;
}

// fused counted-waitcnt + barrier; margin-safe (derivation: R14/R15 journal)
#define WB8() asm volatile("s_waitcnt vmcnt(8)\n\ts_barrier" ::: "memory")
#define WB0() asm volatile("s_waitcnt vmcnt(0)\n\ts_barrier" ::: "memory")

// ---------- prepass 1: x fp32 -> fp16 linear (exact; x was originally fp16) ----------
__global__ __launch_bounds__(256)
void conv_x(const float* __restrict__ X, unsigned short* __restrict__ XH) {
  const size_t i = ((size_t)blockIdx.x * 256 + threadIdx.x) * 8;
  const float4 a = *(const float4*)(X + i);
  const float4 b = *(const float4*)(X + i + 4);
  uint4 o;
  o.x = __builtin_bit_cast(unsigned, __builtin_amdgcn_cvt_pkrtz(a.x, a.y));
  o.y = __builtin_bit_cast(unsigned, __builtin_amdgcn_cvt_pkrtz(a.z, a.w));
  o.z = __builtin_bit_cast(unsigned, __builtin_amdgcn_cvt_pkrtz(b.x, b.y));
  o.w = __builtin_bit_cast(unsigned, __builtin_amdgcn_cvt_pkrtz(b.z, b.w));
  *(uint4*)(XH + i) = o;
}

// ---------- shared 8x8 nibble transpose ----------
static __device__ __forceinline__ void nib_transpose(unsigned* a) {
  #pragma unroll
  for (int i = 0; i < 8; i += 2) {
    unsigned t = ((a[i] >> 4) ^ a[i + 1]) & 0x0F0F0F0Fu;
    a[i + 1] ^= t;  a[i] ^= t << 4;
  }
  #pragma unroll
  for (int g = 0; g < 8; g += 4)
    #pragma unroll
    for (int i = 0; i < 2; ++i) {
      unsigned t = ((a[g + i] >> 8) ^ a[g + i + 2]) & 0x00FF00FFu;
      a[g + i + 2] ^= t;  a[g + i] ^= t << 8;
    }
  #pragma unroll
  for (int i = 0; i < 4; ++i) {
    unsigned t = ((a[i] >> 16) ^ a[i + 4]) & 0x0000FFFFu;
    a[i + 4] ^= t;  a[i] ^= t << 16;
  }
}

// ---------- prepass 2a: repack qweight nibbles K-major (22.5 MB) ----------
__global__ __launch_bounds__(256)
void repack_qw(const int* __restrict__ QW, unsigned* __restrict__ QWR) {
  const int idx = blockIdx.x * 256 + threadIdx.x;
  const int p  = idx % NPACK;
  const int k8 = idx / NPACK;
  unsigned a[8];
  #pragma unroll
  for (int i = 0; i < 8; ++i)
    a[i] = (unsigned)QW[(size_t)(k8 * 8 + i) * NPACK + p];
  nib_transpose(a);
  const int REV[8] = {0, 4, 1, 5, 2, 6, 3, 7};
  #pragma unroll
  for (int j = 0; j < 8; ++j)
    QWR[(size_t)k8 * N_DIM + 8 * p + j] = a[REV[j]];
}

// ---------- prepass 2b: repack qweight BYTES K-major (45 MB) ----------
// QW8[k8*N + n] = uint2 of bytes {q(k=8k8)..q(8k8+7)} for column n
__global__ __launch_bounds__(256)
void repack_qw8(const int* __restrict__ QW, uint2* __restrict__ QW8) {
  const int idx = blockIdx.x * 256 + threadIdx.x;
  const int p  = idx % NPACK;
  const int k8 = idx / NPACK;
  unsigned a[8];
  #pragma unroll
  for (int i = 0; i < 8; ++i)
    a[i] = (unsigned)QW[(size_t)(k8 * 8 + i) * NPACK + p];
  nib_transpose(a);
  const int REV[8] = {0, 4, 1, 5, 2, 6, 3, 7};
  #pragma unroll
  for (int j = 0; j < 8; ++j) {
    const unsigned d  = a[REV[j]];
    const unsigned lo = d & 0x0F0F0F0Fu;          // bytes [n0,n2,n4,n6]
    const unsigned hi = (d >> 4) & 0x0F0F0F0Fu;   // bytes [n1,n3,n5,n7]
    uint2 o;
    o.x = __builtin_amdgcn_perm(hi, lo, 0x05010400u);  // [n0,n1,n2,n3]
    o.y = __builtin_amdgcn_perm(hi, lo, 0x07030602u);  // [n4,n5,n6,n7]
    QW8[(size_t)k8 * N_DIM + 8 * p + j] = o;
  }
}

// ---------- main: v8 skeleton; BYTE=1: 12-inst dequant; BYTE=0: 19-inst ----------
template <bool BYTE>
__global__ __launch_bounds__(256, 2)
void awq_gemm_v9(const unsigned short* __restrict__ XH,
                 const void* __restrict__ QWP,
                 const int* __restrict__ QZ,
                 const float* __restrict__ S,
                 const float* __restrict__ BIAS,
                 float* __restrict__ OUT)
{
  __shared__ unsigned short Ab0[ATILE];
  __shared__ unsigned short Ab1[ATILE];
  __shared__ unsigned short Ab2[ATILE];

  const int tid  = threadIdx.x;
  const int lane = tid & 63;
  const int wid  = tid >> 6;      // 0..3 = wave column
  const int l31  = lane & 31;
  const int hi   = lane >> 5;

  const int row0 = blockIdx.y * BM;
  const int n0   = blockIdx.x * BN;
  const int col  = n0 + wid * 32 + l31;

  const int jz   = col & 7;
  const int sh_z = (((jz >> 1) | ((jz & 1) << 2)) << 2);

  // ---- hoisted stage pointers ----
  const unsigned short* bptr[4];
  #pragma unroll
  for (int i = 0; i < 4; ++i) {
    const int g = i * 256 + tid;
    const unsigned r = (unsigned)(g >> 3), c = (unsigned)(g & 7);
    bptr[i] = XH + (size_t)(row0 + r) * K_DIM + ((c ^ swz(r)) << 3);
  }

  // ---- hoisted A-frag LDS byte offsets ----
  unsigned aoff[4][4];
  #pragma unroll
  for (int mf = 0; mf < 4; ++mf) {
    const unsigned r = (unsigned)(mf * 32 + l31);
    #pragma unroll
    for (int ks = 0; ks < 4; ++ks)
      aoff[mf][ks] = r * 128 + (((unsigned)(ks * 2 + hi) ^ swz(r)) << 4);
  }

  // ---- hoisted B pointers ----
  const uint2*    pbb[4];
  const unsigned* pbn[4];
  #pragma unroll
  for (int ks = 0; ks < 4; ++ks) {
    if constexpr (BYTE)
      pbb[ks] = (const uint2*)QWP + (size_t)(ks * 2 + hi) * N_DIM + col;
    else
      pbn[ks] = (const unsigned*)QWP + (size_t)(ks * 2 + hi) * N_DIM + col;
  }

  f32x16 acc0 = (f32x16)(0.f), acc1 = (f32x16)(0.f);
  f32x16 acc2 = (f32x16)(0.f), acc3 = (f32x16)(0.f);

  unsigned zz, ss;
  unsigned qn; float sn;
  uint2 bq0[4], bq1[4], bq2[4];

  auto stageA = [&](unsigned short* buf) {
    #pragma unroll
    for (int i = 0; i < 4; ++i) {
      __builtin_amdgcn_global_load_lds(
          (const __attribute__((address_space(1))) void*)bptr[i],
          (__attribute__((address_space(3))) void*)(buf + i * 2048 + wid * 512),
          16, 0, 0);
      bptr[i] += BK;
    }
  };
  auto loadB = [&](uint2* dst) {
    #pragma unroll
    for (int ks = 0; ks < 4; ++ks) {
      if constexpr (BYTE) {
        dst[ks] = *pbb[ks];
        pbb[ks] += (size_t)8 * N_DIM;
      } else {
        dst[ks].x = *pbn[ks];
        pbn[ks] += (size_t)8 * N_DIM;
      }
    }
  };
  auto prepLoad = [&](int grp) {
    qn = (unsigned)QZ[grp * NPACK + (col >> 3)];
    sn = S[(size_t)grp * N_DIM + col];
  };
  auto prepCalc = [&]() {
    const unsigned z = (qn >> sh_z) & 15u;
    zz = z * 0x10001u + 0x64006400u;
    ss = __builtin_bit_cast(unsigned, __builtin_amdgcn_cvt_pkrtz(sn, sn));
  };

  auto compute = [&](const unsigned short* Abuf, const uint2* bq) {
    #pragma unroll
    for (int ks = 0; ks < 4; ++ks) {
      union { unsigned u[4]; f16x8 v; } bf;
      if constexpr (BYTE) {
        // bytes q0..q7; one perm builds [q,0x64,q',0x64] = fp16(1024+q),(1024+q')
        const unsigned C64 = 0x64646464u;
        unsigned h0 = __builtin_amdgcn_perm(C64, bq[ks].x, 0x04010400u);
        unsigned h1 = __builtin_amdgcn_perm(C64, bq[ks].x, 0x04030402u);
        unsigned h2v = __builtin_amdgcn_perm(C64, bq[ks].y, 0x04010400u);
        unsigned h3 = __builtin_amdgcn_perm(C64, bq[ks].y, 0x04030402u);
        bf.u[0] = __builtin_bit_cast(unsigned,
            (__builtin_bit_cast(h2, h0) - __builtin_bit_cast(h2, zz)) * __builtin_bit_cast(h2, ss));
        bf.u[1] = __builtin_bit_cast(unsigned,
            (__builtin_bit_cast(h2, h1) - __builtin_bit_cast(h2, zz)) * __builtin_bit_cast(h2, ss));
        bf.u[2] = __builtin_bit_cast(unsigned,
            (__builtin_bit_cast(h2, h2v) - __builtin_bit_cast(h2, zz)) * __builtin_bit_cast(h2, ss));
        bf.u[3] = __builtin_bit_cast(unsigned,
            (__builtin_bit_cast(h2, h3) - __builtin_bit_cast(h2, zz)) * __builtin_bit_cast(h2, ss));
      } else {
        const unsigned w = bq[ks].x;
        const unsigned e = w & 0x0F0F0F0Fu;
        const unsigned o = (w >> 4) & 0x0F0F0F0Fu;
        #pragma unroll
        for (int q = 0; q < 4; ++q) {
          const unsigned sel = 0x0C000C00u | (unsigned)q | ((unsigned)(4 + q) << 16);
          const unsigned hv  = __builtin_amdgcn_perm(o, e, sel) | 0x64006400u;
          bf.u[q] = __builtin_bit_cast(unsigned,
              (__builtin_bit_cast(h2, hv) - __builtin_bit_cast(h2, zz)) * __builtin_bit_cast(h2, ss));
        }
      }
      __builtin_amdgcn_s_setprio(1);
      acc0 = __builtin_amdgcn_mfma_f32_32x32x16_f16(
          *(const f16x8*)((const char*)Abuf + aoff[0][ks]), bf.v, acc0, 0, 0, 0);
      acc1 = __builtin_amdgcn_mfma_f32_32x32x16_f16(
          *(const f16x8*)((const char*)Abuf + aoff[1][ks]), bf.v, acc1, 0, 0, 0);
      acc2 = __builtin_amdgcn_mfma_f32_32x32x16_f16(
          *(const f16x8*)((const char*)Abuf + aoff[2][ks]), bf.v, acc2, 0, 0, 0);
      acc3 = __builtin_amdgcn_mfma_f32_32x32x16_f16(
          *(const f16x8*)((const char*)Abuf + aoff[3][ks]), bf.v, acc3, 0, 0, 0);
      __builtin_amdgcn_s_setprio(0);
    }
  };

  // ---------------- prologue: stage tiles 0,1 (depth 2) ----------------
  prepLoad(0);
  stageA(Ab0);  loadB(bq0);     // tile 0
  stageA(Ab1);  loadB(bq1);     // tile 1
  WB0();

  // ---------------- main loop: t = 0..59 as 10 x 6 bodies ----------------
  for (int I = 0; I < 10; ++I) {
    const int g3 = 3 * I;
    prepCalc(); stageA(Ab2); loadB(bq2); compute(Ab0, bq0); WB8();
    stageA(Ab0); loadB(bq0); prepLoad(g3 + 1); compute(Ab1, bq1); WB8();
    prepCalc(); stageA(Ab1); loadB(bq1); compute(Ab2, bq2); WB8();
    stageA(Ab2); loadB(bq2); prepLoad(g3 + 2); compute(Ab0, bq0); WB8();
    prepCalc(); stageA(Ab0); loadB(bq0); compute(Ab1, bq1); WB8();
    stageA(Ab1); loadB(bq1); prepLoad(g3 + 3); compute(Ab2, bq2); WB8();
  }

  // ---------------- tail: tiles 60..63 ----------------
  prepCalc(); stageA(Ab2); loadB(bq2); compute(Ab0, bq0); WB8();
  stageA(Ab0); loadB(bq0); prepLoad(31); compute(Ab1, bq1); WB8();
  prepCalc(); compute(Ab2, bq2); WB0();
  compute(Ab0, bq0);

  // ---------------- epilogue ----------------
  // C/D 32x32 (m74/m101): col = lane&31, row = (reg&3) + 8*(reg>>2) + 4*(lane>>5)
  const float bz = BIAS[col];
  const f32x16* accs[4] = {&acc0, &acc1, &acc2, &acc3};
  #pragma unroll
  for (int mf = 0; mf < 4; ++mf) {
    const int rbase = row0 + mf * 32 + 4 * hi;
    #pragma unroll
    for (int r = 0; r < 16; ++r) {
      const int row = rbase + (r & 3) + 8 * (r >> 2);
      OUT[(size_t)row * N_DIM + col] = (*accs[mf])[r] + bz;
    }
  }
}

// ---------------- fallback (fp32 x, no/small ws) ----------------
__global__ __launch_bounds__(512, 2)
void awq_gemm_fb(const float* __restrict__ XF,
                 const int* __restrict__ QW,
                 const int* __restrict__ QZ,
                 const float* __restrict__ S,
                 const float* __restrict__ BIAS,
                 float* __restrict__ OUT)
{
  __shared__ unsigned short Al[2][256 * 64];
  __shared__ unsigned short Bl[2][256 * 64];

  const int tid = threadIdx.x, lane = tid & 63, wid = tid >> 6;
  const int wr = wid >> 2, wc = wid & 3, l15 = lane & 15, l4 = lane >> 4;
  const int row0 = blockIdx.y * 256, n0 = blockIdx.x * 256, p0 = n0 >> 3;
  const int dq_p = tid & 31, dq_k = (tid >> 5) << 2;

  f32x4 acc[8][4];
  #pragma unroll
  for (int i = 0; i < 8; ++i)
    #pragma unroll
    for (int j = 0; j < 4; ++j) acc[i][j] = (f32x4){0.f, 0.f, 0.f, 0.f};

  const int SH[8] = {0, 16, 4, 20, 8, 24, 12, 28};
  unsigned zz[8], ssv[8];

  auto stageA = [&](int buf, int k0) {
    #pragma unroll
    for (int i = 0; i < 4; ++i) {
      const int g = i * 512 + tid;
      const unsigned r = (unsigned)(g >> 3), c = (unsigned)(g & 7);
      const float* src = XF + (size_t)(row0 + r) * K_DIM + k0 + (c << 3);
      const float4 v0 = *(const float4*)src;
      const float4 v1 = *(const float4*)(src + 4);
      uint4 o;
      o.x = __builtin_bit_cast(unsigned, __builtin_amdgcn_cvt_pkrtz(v0.x, v0.y));
      o.y = __builtin_bit_cast(unsigned, __builtin_amdgcn_cvt_pkrtz(v0.z, v0.w));
      o.z = __builtin_bit_cast(unsigned, __builtin_amdgcn_cvt_pkrtz(v1.x, v1.y));
      o.w = __builtin_bit_cast(unsigned, __builtin_amdgcn_cvt_pkrtz(v1.z, v1.w));
      *(uint4*)((char*)&Al[buf][0] + r * 128 + ((c ^ swz(r)) << 4)) = o;
    }
  };
  auto prepGroup = [&](int grp) {
    const unsigned qzv = (unsigned)QZ[grp * NPACK + p0 + dq_p];
    const float* sp = S + (size_t)grp * N_DIM + n0 + dq_p * 8;
    const float4 sv0 = *(const float4*)sp;
    const float4 sv1 = *(const float4*)(sp + 4);
    const float svf[8] = {sv0.x, sv0.y, sv0.z, sv0.w, sv1.x, sv1.y, sv1.z, sv1.w};
    #pragma unroll
    for (int j = 0; j < 8; ++j) {
      const unsigned z = (qzv >> SH[j]) & 15u;
      zz[j] = z * 0x10001u + 0x64006400u;
      ssv[j] = __builtin_bit_cast(unsigned, __builtin_amdgcn_cvt_pkrtz(svf[j], svf[j]));
    }
  };
  unsigned qwc[4], qwn[4];
  auto loadQW = [&](unsigned* dst, int k0) {
    #pragma unroll
    for (int i = 0; i < 4; ++i)
      dst[i] = (unsigned)QW[(size_t)(k0 + dq_k + i) * NPACK + p0 + dq_p];
  };
  auto deqB = [&](int buf, const unsigned* qw) {
    #pragma unroll
    for (int j = 0; j < 8; ++j) {
      const int sh = SH[j];
      const unsigned q01 = ((qw[0] >> sh) & 15u) | (((qw[1] >> sh) & 15u) << 16) | 0x64006400u;
      const unsigned q23 = ((qw[2] >> sh) & 15u) | (((qw[3] >> sh) & 15u) << 16) | 0x64006400u;
      const h2 w01 = (__builtin_bit_cast(h2, q01) - __builtin_bit_cast(h2, zz[j])) *
                     __builtin_bit_cast(h2, ssv[j]);
      const h2 w23 = (__builtin_bit_cast(h2, q23) - __builtin_bit_cast(h2, zz[j])) *
                     __builtin_bit_cast(h2, ssv[j]);
      uint2 wb;
      wb.x = __builtin_bit_cast(unsigned, w01);
      wb.y = __builtin_bit_cast(unsigned, w23);
      const unsigned nn = dq_p * 8 + j;
      *(uint2*)((char*)&Bl[buf][0] + nn * 128 + ((dq_k * 2) ^ (swz(nn) << 4))) = wb;
    }
  };

  stageA(0, 0); prepGroup(0); loadQW(qwc, 0); deqB(0, qwc); loadQW(qwn, 64);
  __syncthreads();
  int cur = 0;
  for (int t = 0; t < 64; ++t) {
    if (t + 1 < 64) {
      const int kn = (t + 1) * 64;
      stageA(cur ^ 1, kn);
      if (((t + 1) & 1) == 0) prepGroup((t + 1) >> 1);
      deqB(cur ^ 1, qwn);
      if (t + 2 < 64) loadQW(qwn, kn + 64);
    }
    const char* Ac = (const char*)&Al[cur][0];
    const char* Bc = (const char*)&Bl[cur][0];
    #pragma unroll
    for (int kk = 0; kk < 2; ++kk) {
      f16x8 afv[8], bfv[4];
      #pragma unroll
      for (int m = 0; m < 8; ++m) {
        const unsigned r = (unsigned)(wr * 128 + m * 16 + l15);
        afv[m] = *(const f16x8*)(Ac + r * 128 + (((unsigned)(kk * 4 + l4) ^ swz(r)) << 4));
      }
      #pragma unroll
      for (int n = 0; n < 4; ++n) {
        const unsigned r = (unsigned)(wc * 64 + n * 16 + l15);
        bfv[n] = *(const f16x8*)(Bc + r * 128 + (((unsigned)(kk * 4 + l4) ^ swz(r)) << 4));
      }
      #pragma unroll
      for (int m = 0; m < 8; ++m)
        #pragma unroll
        for (int n = 0; n < 4; ++n)
          acc[m][n] = __builtin_amdgcn_mfma_f32_16x16x32_f16(afv[m], bfv[n], acc[m][n], 0, 0, 0);
    }
    __syncthreads();
    cur ^= 1;
  }
  #pragma unroll
  for (int n = 0; n < 4; ++n) {
    const int c2 = n0 + wc * 64 + n * 16 + l15;
    const float bz = BIAS[c2];
    #pragma unroll
    for (int m = 0; m < 8; ++m) {
      const int rbase = row0 + wr * 128 + m * 16 + l4 * 4;
      #pragma unroll
      for (int r = 0; r < 4; ++r)
        OUT[(size_t)(rbase + r) * N_DIM + c2] = acc[m][n][r] + bz;
    }
  }
}

extern "C" void kernel_launch(void* const* d_in, const int* in_sizes, int n_in,
                              void* d_out, int out_size, void* d_ws, size_t ws_size,
                              hipStream_t stream) {
  const float* x = nullptr; const int* qw = nullptr; const int* qz = nullptr;
  const float* s = nullptr; const float* b = nullptr;
  for (int i = 0; i < n_in; ++i) {
    switch (in_sizes[i]) {
      case M_DIM * K_DIM:   x  = (const float*)d_in[i]; break;
      case K_DIM * NPACK:   qw = (const int*)d_in[i];   break;
      case NGROUPS * NPACK: qz = (const int*)d_in[i];   break;
      case NGROUPS * N_DIM: s  = (const float*)d_in[i]; break;
      case N_DIM:           b  = (const float*)d_in[i]; break;
    }
  }
  float* out = (float*)d_out;

  const size_t xh_bytes  = (size_t)M_DIM * K_DIM * 2;          // 8 MiB
  const size_t qwr_bytes = (size_t)K8 * N_DIM * 4;             // 22.5 MiB
  const size_t qw8_bytes = (size_t)K8 * N_DIM * 8;             // 45.1 MiB
  const int repack_blocks = (NPACK * K8) / 256;                // 2752 exact
  dim3 grid(N_DIM / BN, M_DIM / BM);                           // 86 x 8

  if (ws_size >= xh_bytes + qw8_bytes) {
    unsigned short* xh = (unsigned short*)d_ws;
    uint2* qw8 = (uint2*)((char*)d_ws + xh_bytes);
    conv_x<<<(M_DIM * K_DIM) / (256 * 8), 256, 0, stream>>>(x, xh);
    repack_qw8<<<repack_blocks, 256, 0, stream>>>(qw, qw8);
    awq_gemm_v9<true><<<grid, dim3(256), 0, stream>>>(xh, qw8, qz, s, b, out);
  } else if (ws_size >= xh_bytes + qwr_bytes) {
    unsigned short* xh = (unsigned short*)d_ws;
    unsigned* qwr = (unsigned*)((char*)d_ws + xh_bytes);
    conv_x<<<(M_DIM * K_DIM) / (256 * 8), 256, 0, stream>>>(x, xh);
    repack_qw<<<repack_blocks, 256, 0, stream>>>(qw, qwr);
    awq_gemm_v9<false><<<grid, dim3(256), 0, stream>>>(xh, qwr, qz, s, b, out);
  } else {
    awq_gemm_fb<<<dim3(N_DIM / 256, M_DIM / 256), dim3(512), 0, stream>>>(
        x, qw, qz, s, b, out);
  }
}

// Round 17
// 141.565 us; speedup vs baseline: 1.1140x; 1.1140x over previous
//
#include <hip/hip_runtime.h>
#include <stdint.h>

#define M_DIM 1024
#define K_DIM 4096
#define N_DIM 11008
#define NPACK 1376
#define NGROUPS 32
#define K8 (K_DIM / 8)      // 512

#define BM 128
#define BN 128
#define BK 64
#define ATILE (BM * BK)     // 8192 shorts = 16 KiB

typedef __attribute__((ext_vector_type(16))) float f32x16;
typedef __attribute__((ext_vector_type(4))) float f32x4;
typedef __attribute__((ext_vector_type(8))) _Float16 f16x8;
typedef __attribute__((ext_vector_type(2))) _Float16 h2;

static __device__ __forceinline__ unsigned swz(unsigned r) {
  return (r ^ (r >> 3)) & 7u;
}

// fused counted-waitcnt + barrier; margin-safe (derivation: R14 journal)
#define WB8() asm volatile("s_waitcnt vmcnt(8)\n\ts_barrier" ::: "memory")
#define WB0() asm volatile("s_waitcnt vmcnt(0)\n\ts_barrier" ::: "memory")

// ---------- prepass 1: x fp32 -> fp16 linear (exact; x was originally fp16) ----------
__global__ __launch_bounds__(256)
void conv_x(const float* __restrict__ X, unsigned short* __restrict__ XH) {
  const size_t i = ((size_t)blockIdx.x * 256 + threadIdx.x) * 8;
  const float4 a = *(const float4*)(X + i);
  const float4 b = *(const float4*)(X + i + 4);
  uint4 o;
  o.x = __builtin_bit_cast(unsigned, __builtin_amdgcn_cvt_pkrtz(a.x, a.y));
  o.y = __builtin_bit_cast(unsigned, __builtin_amdgcn_cvt_pkrtz(a.z, a.w));
  o.z = __builtin_bit_cast(unsigned, __builtin_amdgcn_cvt_pkrtz(b.x, b.y));
  o.w = __builtin_bit_cast(unsigned, __builtin_amdgcn_cvt_pkrtz(b.z, b.w));
  *(uint4*)(XH + i) = o;
}

// ---------- prepass 2: repack qweight nibbles K-major per column (22.5 MB) ----------
__global__ __launch_bounds__(256)
void repack_qw(const int* __restrict__ QW, unsigned* __restrict__ QWR) {
  const int idx = blockIdx.x * 256 + threadIdx.x;
  const int p  = idx % NPACK;
  const int k8 = idx / NPACK;
  unsigned a[8];
  #pragma unroll
  for (int i = 0; i < 8; ++i)
    a[i] = (unsigned)QW[(size_t)(k8 * 8 + i) * NPACK + p];
  #pragma unroll
  for (int i = 0; i < 8; i += 2) {
    unsigned t = ((a[i] >> 4) ^ a[i + 1]) & 0x0F0F0F0Fu;
    a[i + 1] ^= t;  a[i] ^= t << 4;
  }
  #pragma unroll
  for (int g = 0; g < 8; g += 4)
    #pragma unroll
    for (int i = 0; i < 2; ++i) {
      unsigned t = ((a[g + i] >> 8) ^ a[g + i + 2]) & 0x00FF00FFu;
      a[g + i + 2] ^= t;  a[g + i] ^= t << 8;
    }
  #pragma unroll
  for (int i = 0; i < 4; ++i) {
    unsigned t = ((a[i] >> 16) ^ a[i + 4]) & 0x0000FFFFu;
    a[i + 4] ^= t;  a[i] ^= t << 16;
  }
  const int REV[8] = {0, 4, 1, 5, 2, 6, 3, 7};
  #pragma unroll
  for (int j = 0; j < 8; ++j)
    QWR[(size_t)k8 * N_DIM + 8 * p + j] = a[REV[j]];
}

// ---------- main: v8 skeleton + A-frag preload + XCD-locality grid ----------
// grid(8, 86): blockIdx.x = by (fastest) -> XCD k owns by=k; XH panel L2-resident.
__global__ __launch_bounds__(256, 2)
void awq_gemm_v10(const unsigned short* __restrict__ XH,
                  const unsigned* __restrict__ QWR,
                  const int* __restrict__ QZ,
                  const float* __restrict__ S,
                  const float* __restrict__ BIAS,
                  float* __restrict__ OUT)
{
  __shared__ unsigned short Ab0[ATILE];
  __shared__ unsigned short Ab1[ATILE];
  __shared__ unsigned short Ab2[ATILE];

  const int tid  = threadIdx.x;
  const int lane = tid & 63;
  const int wid  = tid >> 6;      // 0..3 = wave column
  const int l31  = lane & 31;
  const int hi   = lane >> 5;

  const int row0 = blockIdx.x * BM;   // by (fastest -> XCD-owned)
  const int n0   = blockIdx.y * BN;   // bx
  const int col  = n0 + wid * 32 + l31;

  const int jz   = col & 7;
  const int sh_z = (((jz >> 1) | ((jz & 1) << 2)) << 2);

  // ---- hoisted stage pointers ----
  const unsigned short* bptr[4];
  #pragma unroll
  for (int i = 0; i < 4; ++i) {
    const int g = i * 256 + tid;
    const unsigned r = (unsigned)(g >> 3), c = (unsigned)(g & 7);
    bptr[i] = XH + (size_t)(row0 + r) * K_DIM + ((c ^ swz(r)) << 3);
  }

  // ---- hoisted A-frag LDS byte offsets ----
  unsigned aoff[4][4];
  #pragma unroll
  for (int mf = 0; mf < 4; ++mf) {
    const unsigned r = (unsigned)(mf * 32 + l31);
    #pragma unroll
    for (int ks = 0; ks < 4; ++ks)
      aoff[mf][ks] = r * 128 + (((unsigned)(ks * 2 + hi) ^ swz(r)) << 4);
  }

  // ---- hoisted B pointers ----
  const unsigned* pb[4];
  #pragma unroll
  for (int ks = 0; ks < 4; ++ks)
    pb[ks] = QWR + (size_t)(ks * 2 + hi) * N_DIM + col;

  f32x16 acc0 = (f32x16)(0.f), acc1 = (f32x16)(0.f);
  f32x16 acc2 = (f32x16)(0.f), acc3 = (f32x16)(0.f);

  unsigned zz, ss;
  unsigned qn; float sn;
  unsigned bq0[4], bq1[4], bq2[4];

  auto stageA = [&](unsigned short* buf) {           // 4 glds, bump by BK
    #pragma unroll
    for (int i = 0; i < 4; ++i) {
      __builtin_amdgcn_global_load_lds(
          (const __attribute__((address_space(1))) void*)bptr[i],
          (__attribute__((address_space(3))) void*)(buf + i * 2048 + wid * 512),
          16, 0, 0);
      bptr[i] += BK;
    }
  };
  auto loadB = [&](unsigned* dst) {                  // 4 loads, bump 1 tile
    #pragma unroll
    for (int ks = 0; ks < 4; ++ks) {
      dst[ks] = *pb[ks];
      pb[ks] += (size_t)8 * N_DIM;
    }
  };
  auto prepLoad = [&](int grp) {
    qn = (unsigned)QZ[grp * NPACK + (col >> 3)];
    sn = S[(size_t)grp * N_DIM + col];
  };
  auto prepCalc = [&]() {
    const unsigned z = (qn >> sh_z) & 15u;
    zz = z * 0x10001u + 0x64006400u;
    ss = __builtin_bit_cast(unsigned, __builtin_amdgcn_cvt_pkrtz(sn, sn));
  };

  auto compute = [&](const unsigned short* Abuf, const unsigned* bq) {
    // 1) preload ALL 16 A-fragments: LDS latency off the MFMA critical path
    f16x8 af[16];
    #pragma unroll
    for (int ks = 0; ks < 4; ++ks)
      #pragma unroll
      for (int mf = 0; mf < 4; ++mf)
        af[ks * 4 + mf] = *(const f16x8*)((const char*)Abuf + aoff[mf][ks]);
    // 2) dequant + MFMA stream
    #pragma unroll
    for (int ks = 0; ks < 4; ++ks) {
      const unsigned w = bq[ks];
      const unsigned e = w & 0x0F0F0F0Fu;
      const unsigned o = (w >> 4) & 0x0F0F0F0Fu;
      union { unsigned u[4]; f16x8 v; } bf;
      #pragma unroll
      for (int q = 0; q < 4; ++q) {
        const unsigned sel = 0x0C000C00u | (unsigned)q | ((unsigned)(4 + q) << 16);
        const unsigned hv  = __builtin_amdgcn_perm(o, e, sel) | 0x64006400u;
        bf.u[q] = __builtin_bit_cast(unsigned,
            (__builtin_bit_cast(h2, hv) - __builtin_bit_cast(h2, zz)) *
            __builtin_bit_cast(h2, ss));
      }
      __builtin_amdgcn_s_setprio(1);
      acc0 = __builtin_amdgcn_mfma_f32_32x32x16_f16(af[ks * 4 + 0], bf.v, acc0, 0, 0, 0);
      acc1 = __builtin_amdgcn_mfma_f32_32x32x16_f16(af[ks * 4 + 1], bf.v, acc1, 0, 0, 0);
      acc2 = __builtin_amdgcn_mfma_f32_32x32x16_f16(af[ks * 4 + 2], bf.v, acc2, 0, 0, 0);
      acc3 = __builtin_amdgcn_mfma_f32_32x32x16_f16(af[ks * 4 + 3], bf.v, acc3, 0, 0, 0);
      __builtin_amdgcn_s_setprio(0);
    }
  };

  // ---------------- prologue: stage tiles 0,1 (depth 2) ----------------
  prepLoad(0);
  stageA(Ab0);  loadB(bq0);     // tile 0
  stageA(Ab1);  loadB(bq1);     // tile 1
  WB0();

  // ---------------- main loop: t = 0..59 as 10 x 6 bodies ----------------
  for (int I = 0; I < 10; ++I) {
    const int g3 = 3 * I;
    prepCalc(); stageA(Ab2); loadB(bq2); compute(Ab0, bq0); WB8();
    stageA(Ab0); loadB(bq0); prepLoad(g3 + 1); compute(Ab1, bq1); WB8();
    prepCalc(); stageA(Ab1); loadB(bq1); compute(Ab2, bq2); WB8();
    stageA(Ab2); loadB(bq2); prepLoad(g3 + 2); compute(Ab0, bq0); WB8();
    prepCalc(); stageA(Ab0); loadB(bq0); compute(Ab1, bq1); WB8();
    stageA(Ab1); loadB(bq1); prepLoad(g3 + 3); compute(Ab2, bq2); WB8();
  }

  // ---------------- tail: tiles 60..63 ----------------
  prepCalc(); stageA(Ab2); loadB(bq2); compute(Ab0, bq0); WB8();
  stageA(Ab0); loadB(bq0); prepLoad(31); compute(Ab1, bq1); WB8();
  prepCalc(); compute(Ab2, bq2); WB0();
  compute(Ab0, bq0);

  // ---------------- epilogue ----------------
  // C/D 32x32 (m74/m101): col = lane&31, row = (reg&3) + 8*(reg>>2) + 4*(lane>>5)
  const float bz = BIAS[col];
  const f32x16* accs[4] = {&acc0, &acc1, &acc2, &acc3};
  #pragma unroll
  for (int mf = 0; mf < 4; ++mf) {
    const int rbase = row0 + mf * 32 + 4 * hi;
    #pragma unroll
    for (int r = 0; r < 16; ++r) {
      const int row = rbase + (r & 3) + 8 * (r >> 2);
      OUT[(size_t)row * N_DIM + col] = (*accs[mf])[r] + bz;
    }
  }
}

// ---------------- fallback (fp32 x, no/small ws) ----------------
__global__ __launch_bounds__(512, 2)
void awq_gemm_fb(const float* __restrict__ XF,
                 const int* __restrict__ QW,
                 const int* __restrict__ QZ,
                 const float* __restrict__ S,
                 const float* __restrict__ BIAS,
                 float* __restrict__ OUT)
{
  __shared__ unsigned short Al[2][256 * 64];
  __shared__ unsigned short Bl[2][256 * 64];

  const int tid = threadIdx.x, lane = tid & 63, wid = tid >> 6;
  const int wr = wid >> 2, wc = wid & 3, l15 = lane & 15, l4 = lane >> 4;
  const int row0 = blockIdx.y * 256, n0 = blockIdx.x * 256, p0 = n0 >> 3;
  const int dq_p = tid & 31, dq_k = (tid >> 5) << 2;

  f32x4 acc[8][4];
  #pragma unroll
  for (int i = 0; i < 8; ++i)
    #pragma unroll
    for (int j = 0; j < 4; ++j) acc[i][j] = (f32x4){0.f, 0.f, 0.f, 0.f};

  const int SH[8] = {0, 16, 4, 20, 8, 24, 12, 28};
  unsigned zz[8], ssv[8];

  auto stageA = [&](int buf, int k0) {
    #pragma unroll
    for (int i = 0; i < 4; ++i) {
      const int g = i * 512 + tid;
      const unsigned r = (unsigned)(g >> 3), c = (unsigned)(g & 7);
      const float* src = XF + (size_t)(row0 + r) * K_DIM + k0 + (c << 3);
      const float4 v0 = *(const float4*)src;
      const float4 v1 = *(const float4*)(src + 4);
      uint4 o;
      o.x = __builtin_bit_cast(unsigned, __builtin_amdgcn_cvt_pkrtz(v0.x, v0.y));
      o.y = __builtin_bit_cast(unsigned, __builtin_amdgcn_cvt_pkrtz(v0.z, v0.w));
      o.z = __builtin_bit_cast(unsigned, __builtin_amdgcn_cvt_pkrtz(v1.x, v1.y));
      o.w = __builtin_bit_cast(unsigned, __builtin_amdgcn_cvt_pkrtz(v1.z, v1.w));
      *(uint4*)((char*)&Al[buf][0] + r * 128 + ((c ^ swz(r)) << 4)) = o;
    }
  };
  auto prepGroup = [&](int grp) {
    const unsigned qzv = (unsigned)QZ[grp * NPACK + p0 + dq_p];
    const float* sp = S + (size_t)grp * N_DIM + n0 + dq_p * 8;
    const float4 sv0 = *(const float4*)sp;
    const float4 sv1 = *(const float4*)(sp + 4);
    const float svf[8] = {sv0.x, sv0.y, sv0.z, sv0.w, sv1.x, sv1.y, sv1.z, sv1.w};
    #pragma unroll
    for (int j = 0; j < 8; ++j) {
      const unsigned z = (qzv >> SH[j]) & 15u;
      zz[j] = z * 0x10001u + 0x64006400u;
      ssv[j] = __builtin_bit_cast(unsigned, __builtin_amdgcn_cvt_pkrtz(svf[j], svf[j]));
    }
  };
  unsigned qwc[4], qwn[4];
  auto loadQW = [&](unsigned* dst, int k0) {
    #pragma unroll
    for (int i = 0; i < 4; ++i)
      dst[i] = (unsigned)QW[(size_t)(k0 + dq_k + i) * NPACK + p0 + dq_p];
  };
  auto deqB = [&](int buf, const unsigned* qw) {
    #pragma unroll
    for (int j = 0; j < 8; ++j) {
      const int sh = SH[j];
      const unsigned q01 = ((qw[0] >> sh) & 15u) | (((qw[1] >> sh) & 15u) << 16) | 0x64006400u;
      const unsigned q23 = ((qw[2] >> sh) & 15u) | (((qw[3] >> sh) & 15u) << 16) | 0x64006400u;
      const h2 w01 = (__builtin_bit_cast(h2, q01) - __builtin_bit_cast(h2, zz[j])) *
                     __builtin_bit_cast(h2, ssv[j]);
      const h2 w23 = (__builtin_bit_cast(h2, q23) - __builtin_bit_cast(h2, zz[j])) *
                     __builtin_bit_cast(h2, ssv[j]);
      uint2 wb;
      wb.x = __builtin_bit_cast(unsigned, w01);
      wb.y = __builtin_bit_cast(unsigned, w23);
      const unsigned nn = dq_p * 8 + j;
      *(uint2*)((char*)&Bl[buf][0] + nn * 128 + ((dq_k * 2) ^ (swz(nn) << 4))) = wb;
    }
  };

  stageA(0, 0); prepGroup(0); loadQW(qwc, 0); deqB(0, qwc); loadQW(qwn, 64);
  __syncthreads();
  int cur = 0;
  for (int t = 0; t < 64; ++t) {
    if (t + 1 < 64) {
      const int kn = (t + 1) * 64;
      stageA(cur ^ 1, kn);
      if (((t + 1) & 1) == 0) prepGroup((t + 1) >> 1);
      deqB(cur ^ 1, qwn);
      if (t + 2 < 64) loadQW(qwn, kn + 64);
    }
    const char* Ac = (const char*)&Al[cur][0];
    const char* Bc = (const char*)&Bl[cur][0];
    #pragma unroll
    for (int kk = 0; kk < 2; ++kk) {
      f16x8 afv[8], bfv[4];
      #pragma unroll
      for (int m = 0; m < 8; ++m) {
        const unsigned r = (unsigned)(wr * 128 + m * 16 + l15);
        afv[m] = *(const f16x8*)(Ac + r * 128 + (((unsigned)(kk * 4 + l4) ^ swz(r)) << 4));
      }
      #pragma unroll
      for (int n = 0; n < 4; ++n) {
        const unsigned r = (unsigned)(wc * 64 + n * 16 + l15);
        bfv[n] = *(const f16x8*)(Bc + r * 128 + (((unsigned)(kk * 4 + l4) ^ swz(r)) << 4));
      }
      #pragma unroll
      for (int m = 0; m < 8; ++m)
        #pragma unroll
        for (int n = 0; n < 4; ++n)
          acc[m][n] = __builtin_amdgcn_mfma_f32_16x16x32_f16(afv[m], bfv[n], acc[m][n], 0, 0, 0);
    }
    __syncthreads();
    cur ^= 1;
  }
  #pragma unroll
  for (int n = 0; n < 4; ++n) {
    const int c2 = n0 + wc * 64 + n * 16 + l15;
    const float bz = BIAS[c2];
    #pragma unroll
    for (int m = 0; m < 8; ++m) {
      const int rbase = row0 + wr * 128 + m * 16 + l4 * 4;
      #pragma unroll
      for (int r = 0; r < 4; ++r)
        OUT[(size_t)(rbase + r) * N_DIM + c2] = acc[m][n][r] + bz;
    }
  }
}

extern "C" void kernel_launch(void* const* d_in, const int* in_sizes, int n_in,
                              void* d_out, int out_size, void* d_ws, size_t ws_size,
                              hipStream_t stream) {
  const float* x = nullptr; const int* qw = nullptr; const int* qz = nullptr;
  const float* s = nullptr; const float* b = nullptr;
  for (int i = 0; i < n_in; ++i) {
    switch (in_sizes[i]) {
      case M_DIM * K_DIM:   x  = (const float*)d_in[i]; break;
      case K_DIM * NPACK:   qw = (const int*)d_in[i];   break;
      case NGROUPS * NPACK: qz = (const int*)d_in[i];   break;
      case NGROUPS * N_DIM: s  = (const float*)d_in[i]; break;
      case N_DIM:           b  = (const float*)d_in[i]; break;
    }
  }
  float* out = (float*)d_out;

  const size_t xh_bytes  = (size_t)M_DIM * K_DIM * 2;          // 8 MiB
  const size_t qwr_bytes = (size_t)K8 * N_DIM * 4;             // 22.5 MiB
  const int repack_blocks = (NPACK * K8) / 256;                // 2752 exact

  if (ws_size >= xh_bytes + qwr_bytes) {
    unsigned short* xh = (unsigned short*)d_ws;
    unsigned* qwr = (unsigned*)((char*)d_ws + xh_bytes);
    conv_x<<<(M_DIM * K_DIM) / (256 * 8), 256, 0, stream>>>(x, xh);
    repack_qw<<<repack_blocks, 256, 0, stream>>>(qw, qwr);
    // grid(8, 86): by fastest -> XCD k owns by=k (XH panel L2-resident)
    awq_gemm_v10<<<dim3(M_DIM / BM, N_DIM / BN), dim3(256), 0, stream>>>(
        xh, qwr, qz, s, b, out);
  } else {
    awq_gemm_fb<<<dim3(N_DIM / 256, M_DIM / 256), dim3(512), 0, stream>>>(
        x, qw, qz, s, b, out);
  }
}

// Round 18
// 123.996 us; speedup vs baseline: 1.2718x; 1.1417x over previous
//
#include <hip/hip_runtime.h>
#include <stdint.h>

#define M_DIM 1024
#define K_DIM 4096
#define N_DIM 11008
#define NPACK 1376
#define NGROUPS 32
#define K8 (K_DIM / 8)      // 512

#define BM 128
#define BN 128
#define BK 64
#define ATILE (BM * BK)     // 8192 shorts = 16 KiB

typedef __attribute__((ext_vector_type(16))) float f32x16;
typedef __attribute__((ext_vector_type(4))) float f32x4;
typedef __attribute__((ext_vector_type(8))) _Float16 f16x8;
typedef __attribute__((ext_vector_type(2))) _Float16 h2;

static __device__ __forceinline__ unsigned swz(unsigned r) {
  return (r ^ (r >> 3)) & 7u;
}

// fused counted-waitcnt + barrier; margin-safe (derivation: R14 journal)
#define WB8() asm volatile("s_waitcnt vmcnt(8)\n\ts_barrier" ::: "memory")
#define WB0() asm volatile("s_waitcnt vmcnt(0)\n\ts_barrier" ::: "memory")

// ---------- prepass 1: x fp32 -> fp16 linear (exact; x was originally fp16) ----------
__global__ __launch_bounds__(256)
void conv_x(const float* __restrict__ X, unsigned short* __restrict__ XH) {
  const size_t i = ((size_t)blockIdx.x * 256 + threadIdx.x) * 8;
  const float4 a = *(const float4*)(X + i);
  const float4 b = *(const float4*)(X + i + 4);
  uint4 o;
  o.x = __builtin_bit_cast(unsigned, __builtin_amdgcn_cvt_pkrtz(a.x, a.y));
  o.y = __builtin_bit_cast(unsigned, __builtin_amdgcn_cvt_pkrtz(a.z, a.w));
  o.z = __builtin_bit_cast(unsigned, __builtin_amdgcn_cvt_pkrtz(b.x, b.y));
  o.w = __builtin_bit_cast(unsigned, __builtin_amdgcn_cvt_pkrtz(b.z, b.w));
  *(uint4*)(XH + i) = o;
}

// ---------- prepass 2: repack qweight nibbles K-major per column (22.5 MB) ----------
__global__ __launch_bounds__(256)
void repack_qw(const int* __restrict__ QW, unsigned* __restrict__ QWR) {
  const int idx = blockIdx.x * 256 + threadIdx.x;
  const int p  = idx % NPACK;
  const int k8 = idx / NPACK;
  unsigned a[8];
  #pragma unroll
  for (int i = 0; i < 8; ++i)
    a[i] = (unsigned)QW[(size_t)(k8 * 8 + i) * NPACK + p];
  #pragma unroll
  for (int i = 0; i < 8; i += 2) {
    unsigned t = ((a[i] >> 4) ^ a[i + 1]) & 0x0F0F0F0Fu;
    a[i + 1] ^= t;  a[i] ^= t << 4;
  }
  #pragma unroll
  for (int g = 0; g < 8; g += 4)
    #pragma unroll
    for (int i = 0; i < 2; ++i) {
      unsigned t = ((a[g + i] >> 8) ^ a[g + i + 2]) & 0x00FF00FFu;
      a[g + i + 2] ^= t;  a[g + i] ^= t << 8;
    }
  #pragma unroll
  for (int i = 0; i < 4; ++i) {
    unsigned t = ((a[i] >> 16) ^ a[i + 4]) & 0x0000FFFFu;
    a[i + 4] ^= t;  a[i] ^= t << 16;
  }
  const int REV[8] = {0, 4, 1, 5, 2, 6, 3, 7};
  #pragma unroll
  for (int j = 0; j < 8; ++j)
    QWR[(size_t)k8 * N_DIM + 8 * p + j] = a[REV[j]];
}

// ---------- main: R11-v4 structure + 3-buffer depth-2 pipeline + WB(8) ----------
__global__ __launch_bounds__(256, 2)
void awq_gemm_v8(const unsigned short* __restrict__ XH,
                 const unsigned* __restrict__ QWR,
                 const int* __restrict__ QZ,
                 const float* __restrict__ S,
                 const float* __restrict__ BIAS,
                 float* __restrict__ OUT)
{
  __shared__ unsigned short Ab0[ATILE];
  __shared__ unsigned short Ab1[ATILE];
  __shared__ unsigned short Ab2[ATILE];

  const int tid  = threadIdx.x;
  const int lane = tid & 63;
  const int wid  = tid >> 6;      // 0..3 = wave column
  const int l31  = lane & 31;
  const int hi   = lane >> 5;

  const int row0 = blockIdx.y * BM;
  const int n0   = blockIdx.x * BN;
  const int col  = n0 + wid * 32 + l31;

  const int jz   = col & 7;
  const int sh_z = (((jz >> 1) | ((jz & 1) << 2)) << 2);

  // ---- hoisted stage pointers: granule g = i*256+tid ----
  const unsigned short* bptr[4];
  #pragma unroll
  for (int i = 0; i < 4; ++i) {
    const int g = i * 256 + tid;
    const unsigned r = (unsigned)(g >> 3), c = (unsigned)(g & 7);
    bptr[i] = XH + (size_t)(row0 + r) * K_DIM + ((c ^ swz(r)) << 3);
  }

  // ---- hoisted A-frag LDS byte offsets ----
  unsigned aoff[4][4];
  #pragma unroll
  for (int mf = 0; mf < 4; ++mf) {
    const unsigned r = (unsigned)(mf * 32 + l31);
    #pragma unroll
    for (int ks = 0; ks < 4; ++ks)
      aoff[mf][ks] = r * 128 + (((unsigned)(ks * 2 + hi) ^ swz(r)) << 4);
  }

  // ---- hoisted B pointers ----
  const unsigned* pb[4];
  #pragma unroll
  for (int ks = 0; ks < 4; ++ks)
    pb[ks] = QWR + (size_t)(ks * 2 + hi) * N_DIM + col;

  f32x16 acc0 = (f32x16)(0.f), acc1 = (f32x16)(0.f);
  f32x16 acc2 = (f32x16)(0.f), acc3 = (f32x16)(0.f);

  unsigned zz, ss;
  unsigned qn; float sn;
  unsigned bq0[4], bq1[4], bq2[4];

  auto stageA = [&](unsigned short* buf) {           // 4 glds, bump by BK
    #pragma unroll
    for (int i = 0; i < 4; ++i) {
      __builtin_amdgcn_global_load_lds(
          (const __attribute__((address_space(1))) void*)bptr[i],
          (__attribute__((address_space(3))) void*)(buf + i * 2048 + wid * 512),
          16, 0, 0);
      bptr[i] += BK;
    }
  };
  auto loadB = [&](unsigned* dst) {                  // 4 loads, bump 1 tile
    #pragma unroll
    for (int ks = 0; ks < 4; ++ks) {
      dst[ks] = *pb[ks];
      pb[ks] += (size_t)8 * N_DIM;
    }
  };
  auto prepLoad = [&](int grp) {
    qn = (unsigned)QZ[grp * NPACK + (col >> 3)];
    sn = S[(size_t)grp * N_DIM + col];
  };
  auto prepCalc = [&]() {
    const unsigned z = (qn >> sh_z) & 15u;
    zz = z * 0x10001u + 0x64006400u;
    ss = __builtin_bit_cast(unsigned, __builtin_amdgcn_cvt_pkrtz(sn, sn));
  };

  auto compute = [&](const unsigned short* Abuf, const unsigned* bq) {
    #pragma unroll
    for (int ks = 0; ks < 4; ++ks) {
      const unsigned w = bq[ks];
      const unsigned e = w & 0x0F0F0F0Fu;
      const unsigned o = (w >> 4) & 0x0F0F0F0Fu;
      union { unsigned u[4]; f16x8 v; } bf;
      #pragma unroll
      for (int q = 0; q < 4; ++q) {
        const unsigned sel = 0x0C000C00u | (unsigned)q | ((unsigned)(4 + q) << 16);
        const unsigned hv  = __builtin_amdgcn_perm(o, e, sel) | 0x64006400u;
        const h2 wv = (__builtin_bit_cast(h2, hv) - __builtin_bit_cast(h2, zz)) *
                      __builtin_bit_cast(h2, ss);
        bf.u[q] = __builtin_bit_cast(unsigned, wv);
      }
      acc0 = __builtin_amdgcn_mfma_f32_32x32x16_f16(
          *(const f16x8*)((const char*)Abuf + aoff[0][ks]), bf.v, acc0, 0, 0, 0);
      acc1 = __builtin_amdgcn_mfma_f32_32x32x16_f16(
          *(const f16x8*)((const char*)Abuf + aoff[1][ks]), bf.v, acc1, 0, 0, 0);
      acc2 = __builtin_amdgcn_mfma_f32_32x32x16_f16(
          *(const f16x8*)((const char*)Abuf + aoff[2][ks]), bf.v, acc2, 0, 0, 0);
      acc3 = __builtin_amdgcn_mfma_f32_32x32x16_f16(
          *(const f16x8*)((const char*)Abuf + aoff[3][ks]), bf.v, acc3, 0, 0, 0);
    }
  };

  // ---------------- prologue: stage tiles 0,1 (depth 2) ----------------
  prepLoad(0);
  stageA(Ab0);  loadB(bq0);     // tile 0
  stageA(Ab1);  loadB(bq1);     // tile 1
  WB0();                         // drain all; pipeline warms in first bodies

  // ---------------- main loop: t = 0..59 as 10 x 6 bodies ----------------
  // body t: [even: prepCalc | odd: prepLoad(grp(t+1))]; stage t+2; loadB t+2;
  //         compute t; WB(8).  Margin: A(t+1) always >= 12 deep at WB -> drained.
  for (int I = 0; I < 10; ++I) {
    const int g3 = 3 * I;
    // t = 6I
    prepCalc(); stageA(Ab2); loadB(bq2); compute(Ab0, bq0); WB8();
    // t = 6I+1
    stageA(Ab0); loadB(bq0); prepLoad(g3 + 1); compute(Ab1, bq1); WB8();
    // t = 6I+2
    prepCalc(); stageA(Ab1); loadB(bq1); compute(Ab2, bq2); WB8();
    // t = 6I+3
    stageA(Ab2); loadB(bq2); prepLoad(g3 + 2); compute(Ab0, bq0); WB8();
    // t = 6I+4
    prepCalc(); stageA(Ab0); loadB(bq0); compute(Ab1, bq1); WB8();
    // t = 6I+5
    stageA(Ab1); loadB(bq1); prepLoad(g3 + 3); compute(Ab2, bq2); WB8();
  }

  // ---------------- tail: tiles 60..63 ----------------
  prepCalc(); stageA(Ab2); loadB(bq2); compute(Ab0, bq0); WB8();
  stageA(Ab0); loadB(bq0); prepLoad(31); compute(Ab1, bq1); WB8();
  prepCalc(); compute(Ab2, bq2); WB0();
  compute(Ab0, bq0);

  // ---------------- epilogue ----------------
  // C/D 32x32 (m74/m101): col = lane&31, row = (reg&3) + 8*(reg>>2) + 4*(lane>>5)
  const float bz = BIAS[col];
  const f32x16* accs[4] = {&acc0, &acc1, &acc2, &acc3};
  #pragma unroll
  for (int mf = 0; mf < 4; ++mf) {
    const int rbase = row0 + mf * 32 + 4 * hi;
    #pragma unroll
    for (int r = 0; r < 16; ++r) {
      const int row = rbase + (r & 3) + 8 * (r >> 2);
      OUT[(size_t)row * N_DIM + col] = (*accs[mf])[r] + bz;
    }
  }
}

// ---------------- fallback (fp32 x, no/small ws) ----------------
__global__ __launch_bounds__(512, 2)
void awq_gemm_fb(const float* __restrict__ XF,
                 const int* __restrict__ QW,
                 const int* __restrict__ QZ,
                 const float* __restrict__ S,
                 const float* __restrict__ BIAS,
                 float* __restrict__ OUT)
{
  __shared__ unsigned short Al[2][256 * 64];
  __shared__ unsigned short Bl[2][256 * 64];

  const int tid = threadIdx.x, lane = tid & 63, wid = tid >> 6;
  const int wr = wid >> 2, wc = wid & 3, l15 = lane & 15, l4 = lane >> 4;
  const int row0 = blockIdx.y * 256, n0 = blockIdx.x * 256, p0 = n0 >> 3;
  const int dq_p = tid & 31, dq_k = (tid >> 5) << 2;

  f32x4 acc[8][4];
  #pragma unroll
  for (int i = 0; i < 8; ++i)
    #pragma unroll
    for (int j = 0; j < 4; ++j) acc[i][j] = (f32x4){0.f, 0.f, 0.f, 0.f};

  const int SH[8] = {0, 16, 4, 20, 8, 24, 12, 28};
  unsigned zz[8], ssv[8];

  auto stageA = [&](int buf, int k0) {
    #pragma unroll
    for (int i = 0; i < 4; ++i) {
      const int g = i * 512 + tid;
      const unsigned r = (unsigned)(g >> 3), c = (unsigned)(g & 7);
      const float* src = XF + (size_t)(row0 + r) * K_DIM + k0 + (c << 3);
      const float4 v0 = *(const float4*)src;
      const float4 v1 = *(const float4*)(src + 4);
      uint4 o;
      o.x = __builtin_bit_cast(unsigned, __builtin_amdgcn_cvt_pkrtz(v0.x, v0.y));
      o.y = __builtin_bit_cast(unsigned, __builtin_amdgcn_cvt_pkrtz(v0.z, v0.w));
      o.z = __builtin_bit_cast(unsigned, __builtin_amdgcn_cvt_pkrtz(v1.x, v1.y));
      o.w = __builtin_bit_cast(unsigned, __builtin_amdgcn_cvt_pkrtz(v1.z, v1.w));
      *(uint4*)((char*)&Al[buf][0] + r * 128 + ((c ^ swz(r)) << 4)) = o;
    }
  };
  auto prepGroup = [&](int grp) {
    const unsigned qzv = (unsigned)QZ[grp * NPACK + p0 + dq_p];
    const float* sp = S + (size_t)grp * N_DIM + n0 + dq_p * 8;
    const float4 sv0 = *(const float4*)sp;
    const float4 sv1 = *(const float4*)(sp + 4);
    const float svf[8] = {sv0.x, sv0.y, sv0.z, sv0.w, sv1.x, sv1.y, sv1.z, sv1.w};
    #pragma unroll
    for (int j = 0; j < 8; ++j) {
      const unsigned z = (qzv >> SH[j]) & 15u;
      zz[j] = z * 0x10001u + 0x64006400u;
      ssv[j] = __builtin_bit_cast(unsigned, __builtin_amdgcn_cvt_pkrtz(svf[j], svf[j]));
    }
  };
  unsigned qwc[4], qwn[4];
  auto loadQW = [&](unsigned* dst, int k0) {
    #pragma unroll
    for (int i = 0; i < 4; ++i)
      dst[i] = (unsigned)QW[(size_t)(k0 + dq_k + i) * NPACK + p0 + dq_p];
  };
  auto deqB = [&](int buf, const unsigned* qw) {
    #pragma unroll
    for (int j = 0; j < 8; ++j) {
      const int sh = SH[j];
      const unsigned q01 = ((qw[0] >> sh) & 15u) | (((qw[1] >> sh) & 15u) << 16) | 0x64006400u;
      const unsigned q23 = ((qw[2] >> sh) & 15u) | (((qw[3] >> sh) & 15u) << 16) | 0x64006400u;
      const h2 w01 = (__builtin_bit_cast(h2, q01) - __builtin_bit_cast(h2, zz[j])) *
                     __builtin_bit_cast(h2, ssv[j]);
      const h2 w23 = (__builtin_bit_cast(h2, q23) - __builtin_bit_cast(h2, zz[j])) *
                     __builtin_bit_cast(h2, ssv[j]);
      uint2 wb;
      wb.x = __builtin_bit_cast(unsigned, w01);
      wb.y = __builtin_bit_cast(unsigned, w23);
      const unsigned nn = dq_p * 8 + j;
      *(uint2*)((char*)&Bl[buf][0] + nn * 128 + ((dq_k * 2) ^ (swz(nn) << 4))) = wb;
    }
  };

  stageA(0, 0); prepGroup(0); loadQW(qwc, 0); deqB(0, qwc); loadQW(qwn, 64);
  __syncthreads();
  int cur = 0;
  for (int t = 0; t < 64; ++t) {
    if (t + 1 < 64) {
      const int kn = (t + 1) * 64;
      stageA(cur ^ 1, kn);
      if (((t + 1) & 1) == 0) prepGroup((t + 1) >> 1);
      deqB(cur ^ 1, qwn);
      if (t + 2 < 64) loadQW(qwn, kn + 64);
    }
    const char* Ac = (const char*)&Al[cur][0];
    const char* Bc = (const char*)&Bl[cur][0];
    #pragma unroll
    for (int kk = 0; kk < 2; ++kk) {
      f16x8 afv[8], bfv[4];
      #pragma unroll
      for (int m = 0; m < 8; ++m) {
        const unsigned r = (unsigned)(wr * 128 + m * 16 + l15);
        afv[m] = *(const f16x8*)(Ac + r * 128 + (((unsigned)(kk * 4 + l4) ^ swz(r)) << 4));
      }
      #pragma unroll
      for (int n = 0; n < 4; ++n) {
        const unsigned r = (unsigned)(wc * 64 + n * 16 + l15);
        bfv[n] = *(const f16x8*)(Bc + r * 128 + (((unsigned)(kk * 4 + l4) ^ swz(r)) << 4));
      }
      #pragma unroll
      for (int m = 0; m < 8; ++m)
        #pragma unroll
        for (int n = 0; n < 4; ++n)
          acc[m][n] = __builtin_amdgcn_mfma_f32_16x16x32_f16(afv[m], bfv[n], acc[m][n], 0, 0, 0);
    }
    __syncthreads();
    cur ^= 1;
  }
  #pragma unroll
  for (int n = 0; n < 4; ++n) {
    const int c2 = n0 + wc * 64 + n * 16 + l15;
    const float bz = BIAS[c2];
    #pragma unroll
    for (int m = 0; m < 8; ++m) {
      const int rbase = row0 + wr * 128 + m * 16 + l4 * 4;
      #pragma unroll
      for (int r = 0; r < 4; ++r)
        OUT[(size_t)(rbase + r) * N_DIM + c2] = acc[m][n][r] + bz;
    }
  }
}

extern "C" void kernel_launch(void* const* d_in, const int* in_sizes, int n_in,
                              void* d_out, int out_size, void* d_ws, size_t ws_size,
                              hipStream_t stream) {
  const float* x = nullptr; const int* qw = nullptr; const int* qz = nullptr;
  const float* s = nullptr; const float* b = nullptr;
  for (int i = 0; i < n_in; ++i) {
    switch (in_sizes[i]) {
      case M_DIM * K_DIM:   x  = (const float*)d_in[i]; break;
      case K_DIM * NPACK:   qw = (const int*)d_in[i];   break;
      case NGROUPS * NPACK: qz = (const int*)d_in[i];   break;
      case NGROUPS * N_DIM: s  = (const float*)d_in[i]; break;
      case N_DIM:           b  = (const float*)d_in[i]; break;
    }
  }
  float* out = (float*)d_out;

  const size_t xh_bytes  = (size_t)M_DIM * K_DIM * 2;          // 8 MiB
  const size_t qwr_bytes = (size_t)K8 * N_DIM * 4;             // 22.5 MiB
  const int repack_blocks = (NPACK * K8) / 256;                // 2752 exact

  if (ws_size >= xh_bytes + qwr_bytes) {
    unsigned short* xh = (unsigned short*)d_ws;
    unsigned* qwr = (unsigned*)((char*)d_ws + xh_bytes);
    conv_x<<<(M_DIM * K_DIM) / (256 * 8), 256, 0, stream>>>(x, xh);
    repack_qw<<<repack_blocks, 256, 0, stream>>>(qw, qwr);
    awq_gemm_v8<<<dim3(N_DIM / BN, M_DIM / BM), dim3(256), 0, stream>>>(
        xh, qwr, qz, s, b, out);
  } else {
    awq_gemm_fb<<<dim3(N_DIM / 256, M_DIM / 256), dim3(512), 0, stream>>>(
        x, qw, qz, s, b, out);
  }
}